// Round 5
// baseline (330.161 us; speedup 1.0000x reference)
//
#include <hip/hip_runtime.h>

typedef __bf16 bf16;
typedef __attribute__((ext_vector_type(8))) __bf16 bf16x8;
typedef __attribute__((ext_vector_type(4))) __bf16 bf16x4;
typedef __attribute__((ext_vector_type(4))) float f32x4;
typedef __attribute__((ext_vector_type(4))) unsigned int u32x4;
typedef unsigned int u32;

#define MFMA16(a, b, c) __builtin_amdgcn_mfma_f32_16x16x32_bf16(a, b, c, 0, 0, 0)

__device__ __forceinline__ int div7(int n) { return (n * 37) >> 8; }          // exact 0..63
__device__ __forceinline__ int relv(int n) { return n + 6 * div7(n); }        // 13*(n/7)+(n%7)

#define QSCALE 0.17677669529663687f   // 32^-0.5, folded into Q

__device__ __forceinline__ u32 pack2(float a, float b) {
    unsigned short ua = __builtin_bit_cast(unsigned short, (bf16)a);
    unsigned short ub = __builtin_bit_cast(unsigned short, (bf16)b);
    return (u32)ua | ((u32)ub << 16);
}

// ---------------- prep: pack weights (bf16 MFMA B-frag order) + bake logit tables ---------
// ws layout:
//   bf16x8 frags [0,2304): Wq  [t=0..11][ks=0..2][lane]  (qkv_w)
//                [2304,3456): Wsk [t=0..5][ks=0..2][lane] (skip_w * QSCALE)
//                [3456,4608): Wpr [t=0..5][h=0..2][lane]  (proj_w, permuted quad layout)
//   f32 PB at byte 73728: [vh=12][quad=4][nt=4][q=64][r=4] logit offsets
//     (key = 8*quad + 32*(nt>>1) + 4*(nt&1) + r), vh = variant*3 + h,
//     variant = (wi==31)*2 + (wj==31); value = bias + (-100 mask) + (-20000 key-pad)
__global__ __launch_bounds__(256)
void prep(const float* __restrict__ qkv_w, const float* __restrict__ skip_w,
          const float* __restrict__ proj_w, const float* __restrict__ btab,
          bf16* __restrict__ ws)
{
    const int blk = blockIdx.x, tid = threadIdx.x;
    if (blk < 18) {
        const int j = blk * 256 + tid;
        bf16x8 v;
        if (j < 2304) {
            int t = j / 192, rem = j - t * 192;
            int ks = rem >> 6, lane = rem & 63, q = lane >> 4, l16 = lane & 15;
            const float* p = qkv_w + (16 * t + l16) * 96 + ks * 32 + q * 8;
            #pragma unroll
            for (int e = 0; e < 8; ++e) v[e] = (bf16)p[e];
        } else if (j < 3456) {
            int i = j - 2304;
            int t = i / 192, rem = i - t * 192;
            int ks = rem >> 6, lane = rem & 63, q = lane >> 4, l16 = lane & 15;
            const float* p = skip_w + (16 * t + l16) * 96 + ks * 32 + q * 8;
            #pragma unroll
            for (int e = 0; e < 8; ++e) v[e] = (bf16)(p[e] * QSCALE);
        } else {
            int i = j - 3456;
            int t = i / 192, rem = i - t * 192;
            int h = rem >> 6, lane = rem & 63, q = lane >> 4, l16 = lane & 15;
            const float* p = proj_w + (16 * t + l16) * 96 + 32 * h + 4 * q;
            #pragma unroll
            for (int r = 0; r < 4; ++r) { v[r] = (bf16)p[r]; v[4 + r] = (bf16)p[16 + r]; }
        }
        ((bf16x8*)ws)[j] = v;
    } else {
        const int idx = (blk - 18) * 256 + tid;          // 0..49151
        const int r  = idx & 3;
        const int q  = (idx >> 2) & 63;
        const int nt = (idx >> 8) & 3;
        const int qd = (idx >> 10) & 3;
        const int vh = idx >> 12;                        // variant*3 + h
        const int vr = vh / 3, h = vh - 3 * vr;
        const int ebit = vr >> 1, wbit = vr & 1;         // (wi==31), (wj==31)
        const int k = 8 * qd + 32 * (nt >> 1) + 4 * (nt & 1) + r;
        const int qc = (q < 49) ? q : 48;
        float val;
        if (k >= 49) {
            val = -20000.f;
        } else {
            val = btab[(relv(qc) + relv(48 - k)) * 3 + h];
            int rq = div7(qc), cq = qc - 7 * rq;
            int rk = div7(k),  ck = k - 7 * rk;
            int gq = (ebit ? (rq < 4 ? 3 : 6) : 0) + (wbit ? (cq < 4 ? 1 : 2) : 0);
            int gk = (ebit ? (rk < 4 ? 3 : 6) : 0) + (wbit ? (ck < 4 ? 1 : 2) : 0);
            if (gq != gk) val -= 100.f;
        }
        ((float*)(ws + 36864))[idx] = val;
    }
}

// ---------------- main: one block = one 7x7 window, 256 threads = 4 waves ----------------
__global__ __launch_bounds__(256, 6)
void swin_msa_kernel(const float* __restrict__ x_in,   const float* __restrict__ sx_in,
                     const bf16*  __restrict__ wpk,    const float* __restrict__ qkv_b,
                     const float* __restrict__ skip_b, const float* __restrict__ proj_b,
                     float* __restrict__ out)
{
    // LDS: Kb 64x104 (rho-permuted rows; overlays staged X) + VT 96x72 = 27136 B -> 6 blocks/CU
    __shared__ __align__(16) unsigned short smem[13568];
    bf16* X  = (bf16*)smem;        // 64 x 104 staged x (dead at barrier 2)
    bf16* Kb = (bf16*)smem;        // 64 x 104 (written after barrier 2)
    bf16* VT = (bf16*)smem + 6656; // 96 x 72  (V transposed: [channel][pixel])

    const int tid  = threadIdx.x;
    const int wv   = tid >> 6;
    const int lane = tid & 63;
    const int quad = lane >> 4;
    const int l16  = lane & 15;

    const int win  = blockIdx.x;
    const int bimg = win >> 10;
    const int wrem = win & 1023;
    const int wi   = wrem >> 5;
    const int wj   = wrem & 31;

    const f32x4 zero4 = {0.f, 0.f, 0.f, 0.f};
    const int koff = quad * 8;

    const bf16x8* WQ = (const bf16x8*)wpk + lane;          // + (t*3+ks)*64
    const bf16x8* WS = (const bf16x8*)wpk + 2304 + lane;   // + (t*3+ks)*64
    const bf16x8* WP = (const bf16x8*)wpk + 3456 + lane;   // + (t*3+h)*64

    // my pixel: p = 16*wv + l16
    const int pq  = 16 * wv + l16;
    const int pqc = (pq < 49) ? pq : 48;
    int pr = div7(pqc), pc = pqc - 7 * pr;
    int h0 = wi * 7 + pr + 3; if (h0 >= 224) h0 -= 224;     // roll(-3) gather
    int w0 = wj * 7 + pc + 3; if (w0 >= 224) w0 -= 224;
    const int gbase = ((bimg * 224 + h0) * 224 + w0) * 96;

    // hoist B2's sx loads: latency hides under the X gather
    bf16x8 asx[3];
    #pragma unroll
    for (int ks = 0; ks < 3; ++ks) {
        f32x4 a = __builtin_nontemporal_load((const f32x4*)(sx_in + gbase + ks * 32 + koff));
        f32x4 b = __builtin_nontemporal_load((const f32x4*)(sx_in + gbase + ks * 32 + koff + 4));
        bf16x8 r;
        #pragma unroll
        for (int e = 0; e < 4; ++e) { r[e] = (bf16)a[e]; r[4 + e] = (bf16)b[e]; }
        asx[ks] = r;
    }

    // ---- stage A: cooperative dense gather of X -> LDS (bf16), 4 threads/pixel ----
    {
        const int p   = tid >> 2;
        const int seg = tid & 3;
        const int pcl = (p < 49) ? p : 48;
        int rr = div7(pcl), cc = pcl - 7 * rr;
        int gh = wi * 7 + rr + 3; if (gh >= 224) gh -= 224;
        int gw = wj * 7 + cc + 3; if (gw >= 224) gw -= 224;
        const float* src = x_in + ((bimg * 224 + gh) * 224 + gw) * 96 + seg * 24;
        bf16* dst = X + p * 104 + seg * 24;
        f32x4 a0 = __builtin_nontemporal_load((const f32x4*)src);
        f32x4 a1 = __builtin_nontemporal_load((const f32x4*)(src + 4));
        f32x4 a2 = __builtin_nontemporal_load((const f32x4*)(src + 8));
        f32x4 a3 = __builtin_nontemporal_load((const f32x4*)(src + 12));
        f32x4 a4 = __builtin_nontemporal_load((const f32x4*)(src + 16));
        f32x4 a5 = __builtin_nontemporal_load((const f32x4*)(src + 20));
        bf16x8 w0, w1, w2;
        #pragma unroll
        for (int e = 0; e < 4; ++e) {
            w0[e] = (bf16)a0[e]; w0[4 + e] = (bf16)a1[e];
            w1[e] = (bf16)a2[e]; w1[4 + e] = (bf16)a3[e];
            w2[e] = (bf16)a4[e]; w2[4 + e] = (bf16)a5[e];
        }
        *(bf16x8*)(dst)      = w0;
        *(bf16x8*)(dst + 8)  = w1;
        *(bf16x8*)(dst + 16) = w2;
    }

    // ---- stage B2 (swapped): Q^T in registers; no LDS dependency ----
    // lane holds Q[pixel 16wv+l16][channel 16t+4quad+r]
    u32 pk[6][2];
    {
        f32x4 qa[6];
        #pragma unroll
        for (int t = 0; t < 6; ++t) qa[t] = zero4;
        #pragma unroll
        for (int ks = 0; ks < 3; ++ks)
            #pragma unroll
            for (int t = 0; t < 6; ++t)
                qa[t] = MFMA16(WS[(t * 3 + ks) * 64], asx[ks], qa[t]);
        #pragma unroll
        for (int t = 0; t < 6; ++t) {
            const f32x4 sb = *(const f32x4*)(skip_b + 16 * t + 4 * quad);
            float q0 = qa[t][0] + sb[0] * QSCALE;
            float q1 = qa[t][1] + sb[1] * QSCALE;
            float q2 = qa[t][2] + sb[2] * QSCALE;
            float q3 = qa[t][3] + sb[3] * QSCALE;
            pk[t][0] = pack2(q0, q1);
            pk[t][1] = pack2(q2, q3);
        }
    }
    // in-register transpose -> bq[h] = Q[my pixel][32h+8quad+e], e=0..7 (S-MFMA B-frag)
    bf16x8 bq[3];
    {
        const int a0 = 4 * (32 * (quad & 1) + l16);   // src lane, high-dword-half 0
        const int a1 = a0 + 64;                       // src lane, high-dword-half 1
        const bool mhi = quad >= 2;
        #pragma unroll
        for (int h = 0; h < 3; ++h) {
            u32 r00 = (u32)__builtin_amdgcn_ds_bpermute(a0, (int)pk[2 * h][0]);
            u32 r10 = (u32)__builtin_amdgcn_ds_bpermute(a0, (int)pk[2 * h + 1][0]);
            u32 r01 = (u32)__builtin_amdgcn_ds_bpermute(a0, (int)pk[2 * h][1]);
            u32 r11 = (u32)__builtin_amdgcn_ds_bpermute(a0, (int)pk[2 * h + 1][1]);
            u32 s00 = (u32)__builtin_amdgcn_ds_bpermute(a1, (int)pk[2 * h][0]);
            u32 s10 = (u32)__builtin_amdgcn_ds_bpermute(a1, (int)pk[2 * h + 1][0]);
            u32 s01 = (u32)__builtin_amdgcn_ds_bpermute(a1, (int)pk[2 * h][1]);
            u32 s11 = (u32)__builtin_amdgcn_ds_bpermute(a1, (int)pk[2 * h + 1][1]);
            u32x4 w;
            w[0] = mhi ? r10 : r00;
            w[1] = mhi ? r11 : r01;
            w[2] = mhi ? s10 : s00;
            w[3] = mhi ? s11 : s01;
            bq[h] = __builtin_bit_cast(bf16x8, w);
        }
    }
    __syncthreads();   // barrier 1: X staged

    // ---- stage B1 (N-split): KV = X @ qkv_w^T + b; wave wv owns t = 3wv..3wv+2 ----
    {
        f32x4 acc[4][3];
        #pragma unroll
        for (int m = 0; m < 4; ++m)
            #pragma unroll
            for (int j = 0; j < 3; ++j) acc[m][j] = zero4;
        const int tb = 3 * wv;
        #pragma unroll
        for (int ks = 0; ks < 3; ++ks) {
            bf16x8 a[4];
            #pragma unroll
            for (int m = 0; m < 4; ++m)
                a[m] = *(const bf16x8*)(X + (16 * m + l16) * 104 + ks * 32 + koff);
            #pragma unroll
            for (int j = 0; j < 3; ++j) {
                bf16x8 b = WQ[((tb + j) * 3 + ks) * 64];
                #pragma unroll
                for (int m = 0; m < 4; ++m) acc[m][j] = MFMA16(a[m], b, acc[m][j]);
            }
        }
        if (wv >= 2) {
            // V channels, stored transposed [ch][pixel]; VT region never held X
            #pragma unroll
            for (int j = 0; j < 3; ++j) {
                const int ch = 16 * (tb + j - 6) + l16;
                const float bias = qkv_b[16 * (tb + j) + l16];
                #pragma unroll
                for (int m = 0; m < 4; ++m) {
                    bf16x4 vv;
                    #pragma unroll
                    for (int r = 0; r < 4; ++r) vv[r] = (bf16)(acc[m][j][r] + bias);
                    *(bf16x4*)(VT + ch * 72 + 16 * m + 4 * quad) = vv;
                }
            }
            __syncthreads();   // barrier 2: X reads done
        } else {
            __syncthreads();   // barrier 2: X reads done; K may now overlay X
            // K columns 16*tb..+47, rows rho-permuted by key = 16m+4quad+r
            #pragma unroll
            for (int j = 0; j < 3; ++j) {
                const int col = 16 * (tb + j) + l16;
                const float bias = qkv_b[col];
                #pragma unroll
                for (int m = 0; m < 4; ++m) {
                    const int rho = 32 * (m >> 1) + 16 * (quad & 1) + 8 * (m & 1) + 4 * (quad >> 1);
                    #pragma unroll
                    for (int r = 0; r < 4; ++r)
                        Kb[(rho + r) * 104 + col] = (bf16)(acc[m][j][r] + bias);
                }
            }
        }
    }

    // preload head-0 logit offsets before the barrier (off the serial chain)
    const int variant = ((wi == 31) ? 2 : 0) + ((wj == 31) ? 1 : 0);
    const f32x4* PB4 = (const f32x4*)((const float*)(wpk + 36864));
    const int pb0 = ((variant * 3) * 4 + quad) * 4 * 64 + pq;   // + h*1024 + nt*64
    f32x4 pbv[4];
    #pragma unroll
    for (int nt = 0; nt < 4; ++nt) pbv[nt] = PB4[pb0 + nt * 64];

    __syncthreads();   // barrier 3: Kb/VT visible, read-only hereafter

    // ---- stage C: attention + proj, fully in registers ----
    f32x4 dacc[6];
    #pragma unroll
    for (int t = 0; t < 6; ++t) dacc[t] = zero4;

    #pragma unroll
    for (int h = 0; h < 3; ++h) {
        // S^T = K_perm . Q^T with C = baked logit offsets
        f32x4 s[4];
        #pragma unroll
        for (int nt = 0; nt < 4; ++nt) {
            bf16x8 ak = *(const bf16x8*)(Kb + (16 * nt + l16) * 104 + 32 * h + koff);
            s[nt] = MFMA16(ak, bq[h], pbv[nt]);
        }
        // prefetch next head's offsets while S computes
        f32x4 pbn[4];
        if (h < 2) {
            #pragma unroll
            for (int nt = 0; nt < 4; ++nt) pbn[nt] = PB4[pb0 + (h + 1) * 1024 + nt * 64];
        }
        // max-free softmax: logits are O(1); masks underflow exp to 0 exactly
        float v[16];
        #pragma unroll
        for (int nt = 0; nt < 4; ++nt)
            #pragma unroll
            for (int r = 0; r < 4; ++r) v[nt * 4 + r] = __expf(s[nt][r]);
        float s01 = (v[0] + v[1]) + (v[2] + v[3]);
        float s23 = (v[4] + v[5]) + (v[6] + v[7]);
        float s45 = (v[8] + v[9]) + (v[10] + v[11]);
        float s67 = (v[12] + v[13]) + (v[14] + v[15]);
        float sm = (s01 + s23) + (s45 + s67);
        sm += __shfl_xor(sm, 16);
        sm += __shfl_xor(sm, 32);
        const float isv = 1.0f / sm;

        // PV (operand-swapped): O^T = V^T . P^T ; rho makes B-frag = e[0..7]/e[8..15]
        bf16x8 bp0, bp1;
        #pragma unroll
        for (int j = 0; j < 8; ++j) { bp0[j] = (bf16)v[j]; bp1[j] = (bf16)v[8 + j]; }
        const bf16* vb = VT + (32 * h + l16) * 72 + koff;
        f32x4 o0 = zero4, o1 = zero4;
        o0 = MFMA16(*(const bf16x8*)(vb),                bp0, o0);
        o0 = MFMA16(*(const bf16x8*)(vb + 32),           bp1, o0);
        o1 = MFMA16(*(const bf16x8*)(vb + 16 * 72),      bp0, o1);
        o1 = MFMA16(*(const bf16x8*)(vb + 16 * 72 + 32), bp1, o1);

        // proj (operand-swapped, fused per head): out^T += Wp(:, head h, permuted) . O_h^T
        bf16x8 bo;
        #pragma unroll
        for (int r = 0; r < 4; ++r) { bo[r] = (bf16)(o0[r] * isv); bo[4 + r] = (bf16)(o1[r] * isv); }
        #pragma unroll
        for (int t = 0; t < 6; ++t)
            dacc[t] = MFMA16(WP[(t * 3 + h) * 64], bo, dacc[t]);

        if (h < 2) {
            #pragma unroll
            for (int nt = 0; nt < 4; ++nt) pbv[nt] = pbn[nt];
        }
    }

    // ---- store: out^T rows = channels (16t+4q+r consecutive -> dwordx4), col = my pixel ----
    if (pq < 49) {
        #pragma unroll
        for (int t = 0; t < 6; ++t) {
            const f32x4 pb = *(const f32x4*)(proj_b + 16 * t + 4 * quad);
            f32x4 ov;
            #pragma unroll
            for (int r = 0; r < 4; ++r) ov[r] = dacc[t][r] + pb[r];
            *(f32x4*)(out + gbase + 16 * t + 4 * quad) = ov;
        }
    }
}

extern "C" void kernel_launch(void* const* d_in, const int* in_sizes, int n_in,
                              void* d_out, int out_size, void* d_ws, size_t ws_size,
                              hipStream_t stream) {
    (void)in_sizes; (void)n_in; (void)out_size; (void)ws_size;
    prep<<<dim3(210), dim3(256), 0, stream>>>(
        (const float*)d_in[2], (const float*)d_in[4], (const float*)d_in[6],
        (const float*)d_in[8], (bf16*)d_ws);
    swin_msa_kernel<<<dim3(4096), dim3(256), 0, stream>>>(
        (const float*)d_in[0], (const float*)d_in[1], (const bf16*)d_ws,
        (const float*)d_in[3], (const float*)d_in[5], (const float*)d_in[7],
        (float*)d_out);
}

// Round 6
// 299.182 us; speedup vs baseline: 1.1035x; 1.1035x over previous
//
#include <hip/hip_runtime.h>

typedef __bf16 bf16;
typedef __attribute__((ext_vector_type(8))) __bf16 bf16x8;
typedef __attribute__((ext_vector_type(4))) __bf16 bf16x4;
typedef __attribute__((ext_vector_type(4))) float f32x4;
typedef __attribute__((ext_vector_type(4))) unsigned int u32x4;
typedef unsigned int u32;

#define MFMA16(a, b, c) __builtin_amdgcn_mfma_f32_16x16x32_bf16(a, b, c, 0, 0, 0)

__device__ __forceinline__ int div7(int n) { return (n * 37) >> 8; }          // exact 0..63
__device__ __forceinline__ int relv(int n) { return n + 6 * div7(n); }        // 13*(n/7)+(n%7)

#define QSCALE 0.17677669529663687f   // 32^-0.5, folded into Q

__device__ __forceinline__ u32 pack2(float a, float b) {
    unsigned short ua = __builtin_bit_cast(unsigned short, (bf16)a);
    unsigned short ub = __builtin_bit_cast(unsigned short, (bf16)b);
    return (u32)ua | ((u32)ub << 16);
}

// ---------------- prep: pack weights (bf16 MFMA B-frag order) + bake logit tables ---------
// ws layout:
//   bf16x8 frags [0,2304): Wq  [t=0..11][ks=0..2][lane]  (qkv_w)
//                [2304,3456): Wsk [t=0..5][ks=0..2][lane] (skip_w * QSCALE)
//                [3456,4608): Wpr [t=0..5][h=0..2][lane]  (proj_w, permuted quad layout)
//   f32 PB at byte 73728: [vh=12][quad=4][nt=4][q=64][r=4] logit offsets
//     (key = 8*quad + 32*(nt>>1) + 4*(nt&1) + r), vh = variant*3 + h,
//     variant = (wi==31)*2 + (wj==31); value = bias + (-100 mask) + (-20000 key-pad)
__global__ __launch_bounds__(256)
void prep(const float* __restrict__ qkv_w, const float* __restrict__ skip_w,
          const float* __restrict__ proj_w, const float* __restrict__ btab,
          bf16* __restrict__ ws)
{
    const int blk = blockIdx.x, tid = threadIdx.x;
    if (blk < 18) {
        const int j = blk * 256 + tid;
        bf16x8 v;
        if (j < 2304) {
            int t = j / 192, rem = j - t * 192;
            int ks = rem >> 6, lane = rem & 63, q = lane >> 4, l16 = lane & 15;
            const float* p = qkv_w + (16 * t + l16) * 96 + ks * 32 + q * 8;
            #pragma unroll
            for (int e = 0; e < 8; ++e) v[e] = (bf16)p[e];
        } else if (j < 3456) {
            int i = j - 2304;
            int t = i / 192, rem = i - t * 192;
            int ks = rem >> 6, lane = rem & 63, q = lane >> 4, l16 = lane & 15;
            const float* p = skip_w + (16 * t + l16) * 96 + ks * 32 + q * 8;
            #pragma unroll
            for (int e = 0; e < 8; ++e) v[e] = (bf16)(p[e] * QSCALE);
        } else {
            int i = j - 3456;
            int t = i / 192, rem = i - t * 192;
            int h = rem >> 6, lane = rem & 63, q = lane >> 4, l16 = lane & 15;
            const float* p = proj_w + (16 * t + l16) * 96 + 32 * h + 4 * q;
            #pragma unroll
            for (int r = 0; r < 4; ++r) { v[r] = (bf16)p[r]; v[4 + r] = (bf16)p[16 + r]; }
        }
        ((bf16x8*)ws)[j] = v;
    } else {
        const int idx = (blk - 18) * 256 + tid;          // 0..49151
        const int r  = idx & 3;
        const int q  = (idx >> 2) & 63;
        const int nt = (idx >> 8) & 3;
        const int qd = (idx >> 10) & 3;
        const int vh = idx >> 12;                        // variant*3 + h
        const int vr = vh / 3, h = vh - 3 * vr;
        const int ebit = vr >> 1, wbit = vr & 1;         // (wi==31), (wj==31)
        const int k = 8 * qd + 32 * (nt >> 1) + 4 * (nt & 1) + r;
        const int qc = (q < 49) ? q : 48;
        float val;
        if (k >= 49) {
            val = -20000.f;
        } else {
            val = btab[(relv(qc) + relv(48 - k)) * 3 + h];
            int rq = div7(qc), cq = qc - 7 * rq;
            int rk = div7(k),  ck = k - 7 * rk;
            int gq = (ebit ? (rq < 4 ? 3 : 6) : 0) + (wbit ? (cq < 4 ? 1 : 2) : 0);
            int gk = (ebit ? (rk < 4 ? 3 : 6) : 0) + (wbit ? (ck < 4 ? 1 : 2) : 0);
            if (gq != gk) val -= 100.f;
        }
        ((float*)(ws + 36864))[idx] = val;
    }
}

// ---------------- main: one block = one 7x7 window, 256 threads = 4 waves ----------------
// (256,5): VGPR cap 102 -> no spills (R5's (256,6) cap 85 spilled: WRITE_SIZE 84->276 MB).
// LDS 27136 B x 5 = 132.5 KiB -> 5 blocks/CU.
__global__ __launch_bounds__(256, 5)
void swin_msa_kernel(const float* __restrict__ x_in,   const float* __restrict__ sx_in,
                     const bf16*  __restrict__ wpk,    const float* __restrict__ qkv_b,
                     const float* __restrict__ skip_b, const float* __restrict__ proj_b,
                     float* __restrict__ out)
{
    // LDS: Kb 64x104 (rho-permuted rows; overlays staged X) + VT 96x72 = 27136 B
    __shared__ __align__(16) unsigned short smem[13568];
    bf16* X  = (bf16*)smem;        // 64 x 104 staged x (dead at barrier 2)
    bf16* Kb = (bf16*)smem;        // 64 x 104 (written after barrier 2)
    bf16* VT = (bf16*)smem + 6656; // 96 x 72  (V transposed: [channel][pixel])

    const int tid  = threadIdx.x;
    const int wv   = tid >> 6;
    const int lane = tid & 63;
    const int quad = lane >> 4;
    const int l16  = lane & 15;

    const int win  = blockIdx.x;
    const int bimg = win >> 10;
    const int wrem = win & 1023;
    const int wi   = wrem >> 5;
    const int wj   = wrem & 31;

    const f32x4 zero4 = {0.f, 0.f, 0.f, 0.f};
    const int koff = quad * 8;

    const bf16x8* WQ = (const bf16x8*)wpk + lane;          // + (t*3+ks)*64
    const bf16x8* WS = (const bf16x8*)wpk + 2304 + lane;   // + (t*3+ks)*64
    const bf16x8* WP = (const bf16x8*)wpk + 3456 + lane;   // + (t*3+h)*64

    // my pixel: p = 16*wv + l16
    const int pq  = 16 * wv + l16;
    const int pqc = (pq < 49) ? pq : 48;
    int pr = div7(pqc), pc = pqc - 7 * pr;
    int h0 = wi * 7 + pr + 3; if (h0 >= 224) h0 -= 224;     // roll(-3) gather
    int w0 = wj * 7 + pc + 3; if (w0 >= 224) w0 -= 224;
    const int gbase = ((bimg * 224 + h0) * 224 + w0) * 96;

    // hoist B2's sx loads: latency hides under the X gather
    bf16x8 asx[3];
    #pragma unroll
    for (int ks = 0; ks < 3; ++ks) {
        f32x4 a = __builtin_nontemporal_load((const f32x4*)(sx_in + gbase + ks * 32 + koff));
        f32x4 b = __builtin_nontemporal_load((const f32x4*)(sx_in + gbase + ks * 32 + koff + 4));
        bf16x8 r;
        #pragma unroll
        for (int e = 0; e < 4; ++e) { r[e] = (bf16)a[e]; r[4 + e] = (bf16)b[e]; }
        asx[ks] = r;
    }

    // ---- stage A: cooperative dense gather of X -> LDS (bf16), 4 threads/pixel ----
    {
        const int p   = tid >> 2;
        const int seg = tid & 3;
        const int pcl = (p < 49) ? p : 48;
        int rr = div7(pcl), cc = pcl - 7 * rr;
        int gh = wi * 7 + rr + 3; if (gh >= 224) gh -= 224;
        int gw = wj * 7 + cc + 3; if (gw >= 224) gw -= 224;
        const float* src = x_in + ((bimg * 224 + gh) * 224 + gw) * 96 + seg * 24;
        bf16* dst = X + p * 104 + seg * 24;
        f32x4 a0 = __builtin_nontemporal_load((const f32x4*)src);
        f32x4 a1 = __builtin_nontemporal_load((const f32x4*)(src + 4));
        f32x4 a2 = __builtin_nontemporal_load((const f32x4*)(src + 8));
        f32x4 a3 = __builtin_nontemporal_load((const f32x4*)(src + 12));
        f32x4 a4 = __builtin_nontemporal_load((const f32x4*)(src + 16));
        f32x4 a5 = __builtin_nontemporal_load((const f32x4*)(src + 20));
        bf16x8 w0, w1, w2;
        #pragma unroll
        for (int e = 0; e < 4; ++e) {
            w0[e] = (bf16)a0[e]; w0[4 + e] = (bf16)a1[e];
            w1[e] = (bf16)a2[e]; w1[4 + e] = (bf16)a3[e];
            w2[e] = (bf16)a4[e]; w2[4 + e] = (bf16)a5[e];
        }
        *(bf16x8*)(dst)      = w0;
        *(bf16x8*)(dst + 8)  = w1;
        *(bf16x8*)(dst + 16) = w2;
    }

    // ---- stage B2 (swapped): Q^T in registers; no LDS dependency ----
    // lane holds Q[pixel 16wv+l16][channel 16t+4quad+r]
    u32 pk[6][2];
    {
        f32x4 qa[6];
        #pragma unroll
        for (int t = 0; t < 6; ++t) qa[t] = zero4;
        #pragma unroll
        for (int ks = 0; ks < 3; ++ks)
            #pragma unroll
            for (int t = 0; t < 6; ++t)
                qa[t] = MFMA16(WS[(t * 3 + ks) * 64], asx[ks], qa[t]);
        #pragma unroll
        for (int t = 0; t < 6; ++t) {
            const f32x4 sb = *(const f32x4*)(skip_b + 16 * t + 4 * quad);
            float q0 = qa[t][0] + sb[0] * QSCALE;
            float q1 = qa[t][1] + sb[1] * QSCALE;
            float q2 = qa[t][2] + sb[2] * QSCALE;
            float q3 = qa[t][3] + sb[3] * QSCALE;
            pk[t][0] = pack2(q0, q1);
            pk[t][1] = pack2(q2, q3);
        }
    }
    // in-register transpose -> bq[h] = Q[my pixel][32h+8quad+e], e=0..7 (S-MFMA B-frag)
    bf16x8 bq[3];
    {
        const int a0 = 4 * (32 * (quad & 1) + l16);   // src lane, high-dword-half 0
        const int a1 = a0 + 64;                       // src lane, high-dword-half 1
        const bool mhi = quad >= 2;
        #pragma unroll
        for (int h = 0; h < 3; ++h) {
            u32 r00 = (u32)__builtin_amdgcn_ds_bpermute(a0, (int)pk[2 * h][0]);
            u32 r10 = (u32)__builtin_amdgcn_ds_bpermute(a0, (int)pk[2 * h + 1][0]);
            u32 r01 = (u32)__builtin_amdgcn_ds_bpermute(a0, (int)pk[2 * h][1]);
            u32 r11 = (u32)__builtin_amdgcn_ds_bpermute(a0, (int)pk[2 * h + 1][1]);
            u32 s00 = (u32)__builtin_amdgcn_ds_bpermute(a1, (int)pk[2 * h][0]);
            u32 s10 = (u32)__builtin_amdgcn_ds_bpermute(a1, (int)pk[2 * h + 1][0]);
            u32 s01 = (u32)__builtin_amdgcn_ds_bpermute(a1, (int)pk[2 * h][1]);
            u32 s11 = (u32)__builtin_amdgcn_ds_bpermute(a1, (int)pk[2 * h + 1][1]);
            u32x4 w;
            w[0] = mhi ? r10 : r00;
            w[1] = mhi ? r11 : r01;
            w[2] = mhi ? s10 : s00;
            w[3] = mhi ? s11 : s01;
            bq[h] = __builtin_bit_cast(bf16x8, w);
        }
    }
    __syncthreads();   // barrier 1: X staged

    // ---- stage B1 (N-split): KV = X @ qkv_w^T + b; wave wv owns t = 3wv..3wv+2 ----
    {
        f32x4 acc[4][3];
        #pragma unroll
        for (int m = 0; m < 4; ++m)
            #pragma unroll
            for (int j = 0; j < 3; ++j) acc[m][j] = zero4;
        const int tb = 3 * wv;
        #pragma unroll
        for (int ks = 0; ks < 3; ++ks) {
            bf16x8 a[4];
            #pragma unroll
            for (int m = 0; m < 4; ++m)
                a[m] = *(const bf16x8*)(X + (16 * m + l16) * 104 + ks * 32 + koff);
            #pragma unroll
            for (int j = 0; j < 3; ++j) {
                bf16x8 b = WQ[((tb + j) * 3 + ks) * 64];
                #pragma unroll
                for (int m = 0; m < 4; ++m) acc[m][j] = MFMA16(a[m], b, acc[m][j]);
            }
        }
        if (wv >= 2) {
            // V channels, stored transposed [ch][pixel]; VT region never held X
            #pragma unroll
            for (int j = 0; j < 3; ++j) {
                const int ch = 16 * (tb + j - 6) + l16;
                const float bias = qkv_b[16 * (tb + j) + l16];
                #pragma unroll
                for (int m = 0; m < 4; ++m) {
                    bf16x4 vv;
                    #pragma unroll
                    for (int r = 0; r < 4; ++r) vv[r] = (bf16)(acc[m][j][r] + bias);
                    *(bf16x4*)(VT + ch * 72 + 16 * m + 4 * quad) = vv;
                }
            }
            __syncthreads();   // barrier 2: X reads done
        } else {
            __syncthreads();   // barrier 2: X reads done; K may now overlay X
            // K columns 16*tb..+47, rows rho-permuted by key = 16m+4quad+r
            #pragma unroll
            for (int j = 0; j < 3; ++j) {
                const int col = 16 * (tb + j) + l16;
                const float bias = qkv_b[col];
                #pragma unroll
                for (int m = 0; m < 4; ++m) {
                    const int rho = 32 * (m >> 1) + 16 * (quad & 1) + 8 * (m & 1) + 4 * (quad >> 1);
                    #pragma unroll
                    for (int r = 0; r < 4; ++r)
                        Kb[(rho + r) * 104 + col] = (bf16)(acc[m][j][r] + bias);
                }
            }
        }
    }

    // preload head-0 logit offsets before the barrier (off the serial chain)
    const int variant = ((wi == 31) ? 2 : 0) + ((wj == 31) ? 1 : 0);
    const f32x4* PB4 = (const f32x4*)((const float*)(wpk + 36864));
    const int pb0 = ((variant * 3) * 4 + quad) * 4 * 64 + pq;   // + h*1024 + nt*64
    f32x4 pbv[4];
    #pragma unroll
    for (int nt = 0; nt < 4; ++nt) pbv[nt] = PB4[pb0 + nt * 64];

    __syncthreads();   // barrier 3: Kb/VT visible, read-only hereafter

    // ---- stage C: attention + proj, fully in registers ----
    f32x4 dacc[6];
    #pragma unroll
    for (int t = 0; t < 6; ++t) dacc[t] = zero4;

    #pragma unroll
    for (int h = 0; h < 3; ++h) {
        // S^T = K_perm . Q^T with C = baked logit offsets
        f32x4 s[4];
        #pragma unroll
        for (int nt = 0; nt < 4; ++nt) {
            bf16x8 ak = *(const bf16x8*)(Kb + (16 * nt + l16) * 104 + 32 * h + koff);
            s[nt] = MFMA16(ak, bq[h], pbv[nt]);
        }
        // prefetch next head's offsets while S computes
        f32x4 pbn[4];
        if (h < 2) {
            #pragma unroll
            for (int nt = 0; nt < 4; ++nt) pbn[nt] = PB4[pb0 + (h + 1) * 1024 + nt * 64];
        }
        // max-free softmax: logits are O(1); masks underflow exp to 0 exactly
        float v[16];
        #pragma unroll
        for (int nt = 0; nt < 4; ++nt)
            #pragma unroll
            for (int r = 0; r < 4; ++r) v[nt * 4 + r] = __expf(s[nt][r]);
        float s01 = (v[0] + v[1]) + (v[2] + v[3]);
        float s23 = (v[4] + v[5]) + (v[6] + v[7]);
        float s45 = (v[8] + v[9]) + (v[10] + v[11]);
        float s67 = (v[12] + v[13]) + (v[14] + v[15]);
        float sm = (s01 + s23) + (s45 + s67);
        sm += __shfl_xor(sm, 16);
        sm += __shfl_xor(sm, 32);
        const float isv = 1.0f / sm;

        // PV (operand-swapped): O^T = V^T . P^T ; rho makes B-frag = e[0..7]/e[8..15]
        bf16x8 bp0, bp1;
        #pragma unroll
        for (int j = 0; j < 8; ++j) { bp0[j] = (bf16)v[j]; bp1[j] = (bf16)v[8 + j]; }
        const bf16* vb = VT + (32 * h + l16) * 72 + koff;
        f32x4 o0 = zero4, o1 = zero4;
        o0 = MFMA16(*(const bf16x8*)(vb),                bp0, o0);
        o0 = MFMA16(*(const bf16x8*)(vb + 32),           bp1, o0);
        o1 = MFMA16(*(const bf16x8*)(vb + 16 * 72),      bp0, o1);
        o1 = MFMA16(*(const bf16x8*)(vb + 16 * 72 + 32), bp1, o1);

        // proj (operand-swapped, fused per head): out^T += Wp(:, head h, permuted) . O_h^T
        bf16x8 bo;
        #pragma unroll
        for (int r = 0; r < 4; ++r) { bo[r] = (bf16)(o0[r] * isv); bo[4 + r] = (bf16)(o1[r] * isv); }
        #pragma unroll
        for (int t = 0; t < 6; ++t)
            dacc[t] = MFMA16(WP[(t * 3 + h) * 64], bo, dacc[t]);

        if (h < 2) {
            #pragma unroll
            for (int nt = 0; nt < 4; ++nt) pbv[nt] = pbn[nt];
        }
    }

    // ---- store (NT: write-once) out^T rows = channels (16t+4q+r -> dwordx4), col = pixel ----
    if (pq < 49) {
        #pragma unroll
        for (int t = 0; t < 6; ++t) {
            const f32x4 pb = *(const f32x4*)(proj_b + 16 * t + 4 * quad);
            f32x4 ov;
            #pragma unroll
            for (int r = 0; r < 4; ++r) ov[r] = dacc[t][r] + pb[r];
            __builtin_nontemporal_store(ov, (f32x4*)(out + gbase + 16 * t + 4 * quad));
        }
    }
}

extern "C" void kernel_launch(void* const* d_in, const int* in_sizes, int n_in,
                              void* d_out, int out_size, void* d_ws, size_t ws_size,
                              hipStream_t stream) {
    (void)in_sizes; (void)n_in; (void)out_size; (void)ws_size;
    prep<<<dim3(210), dim3(256), 0, stream>>>(
        (const float*)d_in[2], (const float*)d_in[4], (const float*)d_in[6],
        (const float*)d_in[8], (bf16*)d_ws);
    swin_msa_kernel<<<dim3(4096), dim3(256), 0, stream>>>(
        (const float*)d_in[0], (const float*)d_in[1], (const bf16*)d_ws,
        (const float*)d_in[3], (const float*)d_in[5], (const float*)d_in[7],
        (float*)d_out);
}